// Round 3
// baseline (193.364 us; speedup 1.0000x reference)
//
#include <hip/hip_runtime.h>

// YOLOv1-style loss: S=7, B=2, C=20, L=49, n=16384.
// preds row: [ pcls: 980 | pconf: 98 | pbox: 392 ] = 1470 floats
// labels row: L * [ obj(1) | tcls(20) | tbox(4) ] = 1225 floats
// Weights: NOOBJ=0.5, OBJ=0.5, CLS=0.5, COORD=2.5
//
// R10: fully-coalesced single-chain staging. Evidence: R9 (unconditional
// DIRECT pcls gathers, 80B stride) = 65us, 1.35TB/s, VALU 13%, occ 57%
// -- not BW, not occupancy: TA/L1 line-transaction serialization (~690
// line-touches/wave, 49 lines per float2 gather instr). R8 was faster
// only because gathers were 15%-gated (~7 lines/instr). Harness fill
// kernel: 6.8TB/s at 9% occupancy -> streaming needs no TLP; pattern is
// everything. Fix: stage ALL four regions (labels/pcls/conf/pbox) via
// global_load_lds width=16 (contiguous 16B/lane, ~12 VMEM instr and
// ~190 line-touches per wave), ONE vmcnt(0), branch-free compute from
// LDS (pcls reads ~8-way bank conflict ~= 1us total, acceptable).
// LDS 43.5KB/block -> 3 blk/CU = 12 waves (fill saturates at 3).

#define L_CELLS 49
#define PRED_ROW 1470
#define LAB_ROW 1225
#define CONF_BASE 980
#define BOX_BASE 1078
#define W_NOOBJ 0.5f
#define W_OBJ 0.5f
#define W_CLS 0.5f
#define W_COORD 2.5f
#define INV_S (1.0f / 7.0f)

// float4 slot layout per wave (all align-down +0..3 float shift):
#define LAB_OFS 0    // 308 slots  (1225 fl + shift)
#define PCLS_OFS 308 // 246 slots  (980 fl + shift)
#define CONF_OFS 554 // 26 slots   (98 fl + shift)
#define BOX_OFS 580  // 99 slots   (392 fl + shift; <=12B tail overread,
                     //             verified passing R5-R9)
#define WAVE_SLOTS 680

typedef int __attribute__((address_space(1))) as1_int;
typedef int __attribute__((address_space(3))) as3_int;

__global__ __launch_bounds__(256, 3) void yolo_loss_kernel(
    const float* __restrict__ preds, const float* __restrict__ labels,
    float* __restrict__ ws) {
  __shared__ float4 st[4][WAVE_SLOTS];  // 43,520 B/block -> 3 blk/CU

  const int tid = threadIdx.x;
  const int w = tid >> 6;
  const int lane = tid & 63;
  const int s = blockIdx.x * 4 + w;
  float4* stw = st[w];
  float* stf = (float*)stw;

  // ---- stage EVERYTHING coalesced, direct-to-LDS, one vmcnt chain ----
  // labels row (308 slots)
  size_t g0 = (size_t)s * LAB_ROW;
  size_t ga = g0 & ~(size_t)3;
  int loff = (int)(g0 - ga);
#pragma unroll
  for (int r = 0; r < 5; ++r) {
    int i = lane + 64 * r;
    if (i < 308)
      __builtin_amdgcn_global_load_lds((const as1_int*)(labels + ga + 4 * (size_t)i),
                                       (as3_int*)(stf + 256 * r), 16, 0, 0);
  }
  // pcls region (980 floats, 246 slots; row base 8B-aligned for odd s)
  size_t p0 = (size_t)s * PRED_ROW;
  size_t pa = p0 & ~(size_t)3;
  int poff = (int)(p0 - pa);
#pragma unroll
  for (int r = 0; r < 4; ++r) {
    int i = lane + 64 * r;
    if (i < 246)
      __builtin_amdgcn_global_load_lds((const as1_int*)(preds + pa + 4 * (size_t)i),
                                       (as3_int*)(stf + 4 * PCLS_OFS + 256 * r), 16, 0, 0);
  }
  // conf region (98 floats, 26 slots)
  size_t c0 = p0 + CONF_BASE;
  size_t ca = c0 & ~(size_t)3;
  int coff = (int)(c0 - ca);
  if (lane < 26)
    __builtin_amdgcn_global_load_lds((const as1_int*)(preds + ca + 4 * (size_t)lane),
                                     (as3_int*)(stf + 4 * CONF_OFS), 16, 0, 0);
  // pbox region (392 floats, 99 slots)
  size_t b0 = p0 + BOX_BASE;
  size_t ba = b0 & ~(size_t)3;
  int boff = (int)(b0 - ba);
#pragma unroll
  for (int r = 0; r < 2; ++r) {
    int i = lane + 64 * r;
    if (i < 99)
      __builtin_amdgcn_global_load_lds((const as1_int*)(preds + ba + 4 * (size_t)i),
                                       (as3_int*)(stf + 4 * BOX_OFS + 256 * r), 16, 0, 0);
  }

  // single wait for the whole chain (wave-private LDS: no barrier needed)
  asm volatile("s_waitcnt vmcnt(0)" ::: "memory");
  __builtin_amdgcn_sched_barrier(0);

  const float* lab = stf + loff;                 // lab[25l + k]
  const float* pcf = stf + 4 * PCLS_OFS + poff;  // pcf[20l + j]
  const float* cfp = stf + 4 * CONF_OFS + coff;  // cfp[2l + k]
  const float* bxp = stf + 4 * BOX_OFS + boff;   // bxp[8l + k]

  float acc = 0.0f;
  if (lane < L_CELLS) {
    const int l = lane;
    float c0v = cfp[2 * l], c1v = cfp[2 * l + 1];
    float objf = lab[25 * l];

    // ---- branch-free: compute both paths, select ----
    float noobj_term = W_NOOBJ * (c0v * c0v + c1v * c1v);

    float bx[8];
#pragma unroll
    for (int k = 0; k < 8; ++k) bx[k] = bxp[8 * l + k];
    float tx = lab[25 * l + 21], ty = lab[25 * l + 22];
    float tw = lab[25 * l + 23], th = lab[25 * l + 24];
    float t0 = tx * INV_S, t1 = ty * INV_S, t2 = tw, t3 = th;

    float iou[2], rmse2[2];
#pragma unroll
    for (int b = 0; b < 2; ++b) {
      float o0 = bx[4 * b + 0] * INV_S;
      float o1 = bx[4 * b + 1] * INV_S;
      float o2 = bx[4 * b + 2] * bx[4 * b + 2];
      float o3 = bx[4 * b + 3] * bx[4 * b + 3];
      float left = fmaxf(t0 - 0.5f * t2, o0 - 0.5f * o2);
      float right = fminf(t0 + 0.5f * t2, o0 + 0.5f * o2);
      float top = fmaxf(t1 - 0.5f * t3, o1 - 0.5f * o3);
      float bot = fminf(t1 + 0.5f * t3, o1 + 0.5f * o3);
      float wd = right - left;
      float h = bot - top;
      bool invalid = (wd < 0.0f) || (h < 0.0f);
      float inter = invalid ? 0.0f : wd * h;
      float uni = t2 * t3 + o2 * o3 - inter;
      iou[b] = invalid ? 0.0f : inter / fmaxf(uni, 1e-12f);
      float d0 = t0 - o0, d1 = t1 - o1, d2 = t2 - o2, d3 = t3 - o3;
      rmse2[b] = d0 * d0 + d1 * d1 + d2 * d2 + d3 * d3;  // sqrt monotone
    }

    float max_iou = fmaxf(iou[0], iou[1]);
    // jnp.argmax/argmin: first index wins ties -> strict compare for idx 1
    int best;
    if (max_iou > 0.0f)
      best = (iou[1] > iou[0]) ? 1 : 0;
    else
      best = (rmse2[1] < rmse2[0]) ? 1 : 0;
    float best_iou = iou[best];

    float cb = (best == 0) ? c0v : c1v;
    float co = (best == 0) ? c1v : c0v;
    float db = best_iou - cb;
    float obj_term = W_OBJ * db * db + W_NOOBJ * co * co;

    // cls: both operands from LDS (pcls 8-way bank conflict, accepted)
    float clsacc = 0.0f;
#pragma unroll
    for (int k = 0; k < 10; ++k) {
      float d0 = lab[25 * l + 1 + 2 * k] - pcf[20 * l + 2 * k];
      float d1 = lab[25 * l + 2 + 2 * k] - pcf[20 * l + 2 * k + 1];
      clsacc += d0 * d0 + d1 * d1;
    }
    obj_term += W_CLS * clsacc;

    // coord: (tx, ty, sqrt(tw), sqrt(th)) vs best raw box
    float e0 = tx - bx[best * 4 + 0];
    float e1 = ty - bx[best * 4 + 1];
    float e2 = sqrtf(tw) - bx[best * 4 + 2];
    float e3 = sqrtf(th) - bx[best * 4 + 3];
    obj_term += W_COORD * (e0 * e0 + e1 * e1 + e2 * e2 + e3 * e3);

    acc = (objf != 0.0f) ? obj_term : noobj_term;
  }

  // ---- reduce: wave(64) shuffle -> LDS -> one ws slot per block ----
#pragma unroll
  for (int o = 32; o > 0; o >>= 1) acc += __shfl_down(acc, o);

  __shared__ float wsum[4];
  if (lane == 0) wsum[w] = acc;
  __syncthreads();
  if (tid == 0) ws[blockIdx.x] = wsum[0] + wsum[1] + wsum[2] + wsum[3];
}

__global__ __launch_bounds__(1024) void final_reduce_kernel(
    const float* __restrict__ ws, float* __restrict__ out, int m) {
  float acc = 0.0f;
  for (int i = threadIdx.x; i < m; i += 1024) acc += ws[i];
#pragma unroll
  for (int o = 32; o > 0; o >>= 1) acc += __shfl_down(acc, o);
  __shared__ float wsum[16];
  int wave = threadIdx.x >> 6;
  int lane = threadIdx.x & 63;
  if (lane == 0) wsum[wave] = acc;
  __syncthreads();
  if (threadIdx.x == 0) {
    float sum = 0.0f;
#pragma unroll
    for (int i = 0; i < 16; ++i) sum += wsum[i];
    out[0] = sum;
  }
}

extern "C" void kernel_launch(void* const* d_in, const int* in_sizes, int n_in,
                              void* d_out, int out_size, void* d_ws, size_t ws_size,
                              hipStream_t stream) {
  const float* preds = (const float*)d_in[0];
  const float* labels = (const float*)d_in[1];
  float* out = (float*)d_out;
  float* ws = (float*)d_ws;
  int n = in_sizes[0] / PRED_ROW;  // 16384
  int blocks = n / 4;              // 4096 (wave per sample)

  yolo_loss_kernel<<<blocks, 256, 0, stream>>>(preds, labels, ws);
  final_reduce_kernel<<<1, 1024, 0, stream>>>(ws, out, blocks);
}

// Round 5
// 186.163 us; speedup vs baseline: 1.0387x; 1.0387x over previous
//
#include <hip/hip_runtime.h>

// YOLOv1-style loss: S=7, B=2, C=20, L=49, n=16384.
// preds row: [ pcls: 980 | pconf: 98 | pbox: 392 ] = 1470 floats
// labels row: L * [ obj(1) | tcls(20) | tbox(4) ] = 1225 floats
// Weights: NOOBJ=0.5, OBJ=0.5, CLS=0.5, COORD=2.5
//
// R12 = R11 resubmit (R11 hit an infra failure: "container failed
// twice" during acquire; kernel never measured; audit found no
// hang/fault candidate -- same access patterns as R10 which ran).
//
// R11 theory: minimal line-traffic + single overlapped chain. Evidence:
// R9 and R10 both 65us / 86.7MB FETCH / ~1.4 TB/s at 57% vs 21%
// occupancy with opposite access patterns -> bottleneck is per-CU
// outstanding-read capacity: sustained demand-read LINE traffic pins at
// ~2.7-2.8 TB/s (fill kernel: 6.8 TB/s WRITES at 9% occ -- writes need
// no miss slots). Model: dur ~= 64B*lines/2.8TB/s + idle windows.
// R9/R10: 171 lines/wave = 179MB = 64us (matches). R8 gated: ~111 lines
// = 116MB but 2 SERIAL chains -> ~58us. Fix both: (a) gate pcls/pbox
// (skip 85% of those lines); (b) kill the serial chain with an early
// 1-instr obj-flag gather hitting the SAME lines as the labels stage
// (no extra traffic, completes first in-order -> counted vmcnt releases
// objf -> gated gathers overlap the still-in-flight labels stage);
// (c) 24 waves/CU keeps miss queues full during compute. Predict
// ~45-50us kernel, ~170us total.

#define L_CELLS 49
#define PRED_ROW 1470
#define LAB_ROW 1225
#define CONF_BASE 980
#define BOX_BASE 1078
#define W_NOOBJ 0.5f
#define W_OBJ 0.5f
#define W_CLS 0.5f
#define W_COORD 2.5f
#define INV_S (1.0f / 7.0f)

#define LAB_SLOTS 308  // ceil((3 + 1225)/4); 16B tail overread page-safe
#define WAVE_SLOTS 310 // +pad

typedef int __attribute__((address_space(1))) as1_int;
typedef int __attribute__((address_space(3))) as3_int;

__global__ __launch_bounds__(256, 6) void yolo_loss_kernel(
    const float* __restrict__ preds, const float* __restrict__ labels,
    float* __restrict__ ws) {
  __shared__ float4 st[4][WAVE_SLOTS];  // 19,840 B/block -> 8 blk/CU by LDS

  const int tid = threadIdx.x;
  const int w = tid >> 6;
  const int lane = tid & 63;
  const int s = blockIdx.x * 4 + w;
  float4* stw = st[w];
  float* stf = (float*)stw;

  const float* lrow = labels + (size_t)s * LAB_ROW;
  const float* rp = preds + (size_t)s * PRED_ROW;
  const bool act = lane < L_CELLS;

  // 1) EARLY obj-flag gather: one instr, 49 lines -- the same lines the
  //    labels stage below fetches (no added traffic). First-issued ->
  //    first-complete (in-order vmcnt) -> unblocks gated loads ASAP.
  float objf = 0.0f;
  if (act) objf = lrow[25 * lane];

  // 2) conf: coalesced 8B/lane direct (lane 63 reads rp+1106 < 1470, in-row)
  float2 cf = *(const float2*)(rp + CONF_BASE + 2 * lane);

  // 3) labels stage, coalesced direct-to-LDS (wave-private, no barrier)
  size_t g0 = (size_t)s * LAB_ROW;
  size_t ga = g0 & ~(size_t)3;
  int loff = (int)(g0 - ga);
#pragma unroll
  for (int r = 0; r < 5; ++r) {
    int i = lane + 64 * r;
    if (i < LAB_SLOTS)
      __builtin_amdgcn_global_load_lds((const as1_int*)(labels + ga + 4 * (size_t)i),
                                       (as3_int*)(stf + 256 * r), 16, 0, 0);
  }
  __builtin_amdgcn_sched_barrier(0);  // pin: all stream loads issued first

  // 4) gated gathers -- compiler inserts counted vmcnt for objf only;
  //    labels stage stays in flight underneath.
  const bool objm = act && (objf != 0.0f);
  float2 pc[10];
  float2 bq[4];
  if (objm) {
#pragma unroll
    for (int k = 0; k < 10; ++k)
      pc[k] = *(const float2*)(rp + 20 * lane + 2 * k);  // 8B-aligned
#pragma unroll
    for (int k = 0; k < 4; ++k)
      bq[k] = *(const float2*)(rp + BOX_BASE + 8 * lane + 2 * k);  // 8B-aligned
  }

  // single drain before consuming LDS + gathered regs
  asm volatile("s_waitcnt vmcnt(0)" ::: "memory");
  __builtin_amdgcn_sched_barrier(0);

  const float* lab = stf + loff;  // lab[25l + k]

  float acc = 0.0f;
  if (act) {
    const int l = lane;
    float noobj_term = W_NOOBJ * (cf.x * cf.x + cf.y * cf.y);
    if (objm) {
      float bx[8] = {bq[0].x, bq[0].y, bq[1].x, bq[1].y,
                     bq[2].x, bq[2].y, bq[3].x, bq[3].y};
      float tx = lab[25 * l + 21], ty = lab[25 * l + 22];
      float tw = lab[25 * l + 23], th = lab[25 * l + 24];
      float t0 = tx * INV_S, t1 = ty * INV_S, t2 = tw, t3 = th;

      float iou[2], rmse2[2];
#pragma unroll
      for (int b = 0; b < 2; ++b) {
        float o0 = bx[4 * b + 0] * INV_S;
        float o1 = bx[4 * b + 1] * INV_S;
        float o2 = bx[4 * b + 2] * bx[4 * b + 2];
        float o3 = bx[4 * b + 3] * bx[4 * b + 3];
        float left = fmaxf(t0 - 0.5f * t2, o0 - 0.5f * o2);
        float right = fminf(t0 + 0.5f * t2, o0 + 0.5f * o2);
        float top = fmaxf(t1 - 0.5f * t3, o1 - 0.5f * o3);
        float bot = fminf(t1 + 0.5f * t3, o1 + 0.5f * o3);
        float wd = right - left;
        float h = bot - top;
        bool invalid = (wd < 0.0f) || (h < 0.0f);
        float inter = invalid ? 0.0f : wd * h;
        float uni = t2 * t3 + o2 * o3 - inter;
        iou[b] = invalid ? 0.0f : inter / fmaxf(uni, 1e-12f);
        float d0 = t0 - o0, d1 = t1 - o1, d2 = t2 - o2, d3 = t3 - o3;
        rmse2[b] = d0 * d0 + d1 * d1 + d2 * d2 + d3 * d3;  // sqrt monotone
      }

      float max_iou = fmaxf(iou[0], iou[1]);
      // jnp.argmax/argmin: first index wins ties -> strict compare for idx 1
      int best;
      if (max_iou > 0.0f)
        best = (iou[1] > iou[0]) ? 1 : 0;
      else
        best = (rmse2[1] < rmse2[0]) ? 1 : 0;
      float best_iou = iou[best];

      float cb = (best == 0) ? cf.x : cf.y;
      float co = (best == 0) ? cf.y : cf.x;
      float db = best_iou - cb;
      float obj_term = W_OBJ * db * db + W_NOOBJ * co * co;

      // cls: pcls from gathered regs, tcls from staged labels
      float clsacc = 0.0f;
#pragma unroll
      for (int k = 0; k < 10; ++k) {
        float d0 = lab[25 * l + 1 + 2 * k] - pc[k].x;
        float d1 = lab[25 * l + 2 + 2 * k] - pc[k].y;
        clsacc += d0 * d0 + d1 * d1;
      }
      obj_term += W_CLS * clsacc;

      // coord: (tx, ty, sqrt(tw), sqrt(th)) vs best raw box
      float e0 = tx - bx[best * 4 + 0];
      float e1 = ty - bx[best * 4 + 1];
      float e2 = sqrtf(tw) - bx[best * 4 + 2];
      float e3 = sqrtf(th) - bx[best * 4 + 3];
      obj_term += W_COORD * (e0 * e0 + e1 * e1 + e2 * e2 + e3 * e3);

      acc = obj_term;
    } else {
      acc = noobj_term;
    }
  }

  // ---- reduce: wave(64) shuffle -> LDS -> one ws slot per block ----
#pragma unroll
  for (int o = 32; o > 0; o >>= 1) acc += __shfl_down(acc, o);

  __shared__ float wsum[4];
  if (lane == 0) wsum[w] = acc;
  __syncthreads();
  if (tid == 0) ws[blockIdx.x] = wsum[0] + wsum[1] + wsum[2] + wsum[3];
}

__global__ __launch_bounds__(1024) void final_reduce_kernel(
    const float* __restrict__ ws, float* __restrict__ out, int m) {
  float acc = 0.0f;
  for (int i = threadIdx.x; i < m; i += 1024) acc += ws[i];
#pragma unroll
  for (int o = 32; o > 0; o >>= 1) acc += __shfl_down(acc, o);
  __shared__ float wsum[16];
  int wave = threadIdx.x >> 6;
  int lane = threadIdx.x & 63;
  if (lane == 0) wsum[wave] = acc;
  __syncthreads();
  if (threadIdx.x == 0) {
    float sum = 0.0f;
#pragma unroll
    for (int i = 0; i < 16; ++i) sum += wsum[i];
    out[0] = sum;
  }
}

extern "C" void kernel_launch(void* const* d_in, const int* in_sizes, int n_in,
                              void* d_out, int out_size, void* d_ws, size_t ws_size,
                              hipStream_t stream) {
  const float* preds = (const float*)d_in[0];
  const float* labels = (const float*)d_in[1];
  float* out = (float*)d_out;
  float* ws = (float*)d_ws;
  int n = in_sizes[0] / PRED_ROW;  // 16384
  int blocks = n / 4;              // 4096 (wave per sample)

  yolo_loss_kernel<<<blocks, 256, 0, stream>>>(preds, labels, ws);
  final_reduce_kernel<<<1, 1024, 0, stream>>>(ws, out, blocks);
}